// Round 4
// baseline (146.228 us; speedup 1.0000x reference)
//
#include <hip/hip_runtime.h>

// Problem constants (fixed by reference setup_inputs)
#define B_     64
#define K_     4
#define M_     3
#define NPIX   65536      // X*Y = 256*256
#define CHUNKS 32         // blocks per image -> grid = 2048 = 8 blocks/CU
#define GRID_  (B_ * CHUNKS)
#define TPB    256
#define ITERS  2          // pixels/thread = ITERS*4 = 8
#define NV     16         // 4 den + 12 num partials per thread
#define KM     (K_ * M_)

typedef float f32x4 __attribute__((ext_vector_type(4)));
typedef int   i32x4 __attribute__((ext_vector_type(4)));

// Streaming load with sc1+nt cache policy: non-temporal AND device-scope, so
// the line is not installed in the XCD L2 and (theory) not allocated in the
// MALL. Goal: stop input reads from evicting the harness's 256 MB dirty
// poison out of the MALL (round-2/3 counters: poison writeback steals ~60%
// of HBM BW during this kernel). Ordered-volatile asms batch 8 loads; the
// single vmcnt(0)+sched_barrier below drains them before use (rule #18).
#define STREAM_LOAD(dst, base, voff)                                   \
    asm volatile("global_load_dwordx4 %0, %1, %2 sc1 nt"               \
                 : "=&v"(dst) : "v"(voff), "s"(base))

__global__ __launch_bounds__(TPB) void partial_kernel(
    const float* __restrict__ pred,    // [B,K,NPIX]
    const float* __restrict__ inp,     // [B,M,NPIX]
    const int*   __restrict__ heart,   // [B,NPIX]
    float* __restrict__ ws)            // [GRID_,NV]
{
    const int b     = blockIdx.x >> 5;           // / CHUNKS
    const int chunk = blockIdx.x & (CHUNKS - 1);
    const int voff  = (int)threadIdx.x * 16;     // byte offset within 1024-px span

    // val[0..3] = den[k]; val[4 + k*3 + m] = num[k][m]
    float val[NV];
#pragma unroll
    for (int i = 0; i < NV; ++i) val[i] = 0.0f;

#pragma unroll
    for (int it = 0; it < ITERS; ++it) {
        const int pixbase = chunk * (NPIX / CHUNKS) + it * (TPB * 4);

        const int*   hb = heart + (size_t)b * NPIX + pixbase;
        const float* ib0 = inp + ((size_t)b * M_ + 0) * NPIX + pixbase;
        const float* ib1 = inp + ((size_t)b * M_ + 1) * NPIX + pixbase;
        const float* ib2 = inp + ((size_t)b * M_ + 2) * NPIX + pixbase;
        const float* pb0 = pred + ((size_t)b * K_ + 0) * NPIX + pixbase;
        const float* pb1 = pred + ((size_t)b * K_ + 1) * NPIX + pixbase;
        const float* pb2 = pred + ((size_t)b * K_ + 2) * NPIX + pixbase;
        const float* pb3 = pred + ((size_t)b * K_ + 3) * NPIX + pixbase;

        i32x4 h;
        f32x4 in0, in1, in2, p0, p1, p2, p3;
        STREAM_LOAD(h,   hb,  voff);
        STREAM_LOAD(in0, ib0, voff);
        STREAM_LOAD(in1, ib1, voff);
        STREAM_LOAD(in2, ib2, voff);
        STREAM_LOAD(p0,  pb0, voff);
        STREAM_LOAD(p1,  pb1, voff);
        STREAM_LOAD(p2,  pb2, voff);
        STREAM_LOAD(p3,  pb3, voff);
        asm volatile("s_waitcnt vmcnt(0)" ::: "memory");
        __builtin_amdgcn_sched_barrier(0);

        const float mx = (h.x == 1) ? 1.0f : 0.0f;
        const float my = (h.y == 1) ? 1.0f : 0.0f;
        const float mz = (h.z == 1) ? 1.0f : 0.0f;
        const float mw = (h.w == 1) ? 1.0f : 0.0f;

        f32x4 in[M_] = {in0, in1, in2};
        f32x4 pr[K_] = {p0, p1, p2, p3};

#pragma unroll
        for (int k = 0; k < K_; ++k) {
            f32x4 pm;
            pm.x = pr[k].x * mx; pm.y = pr[k].y * my;
            pm.z = pr[k].z * mz; pm.w = pr[k].w * mw;
            val[k] += (pm.x + pm.y) + (pm.z + pm.w);
#pragma unroll
            for (int m = 0; m < M_; ++m)
                val[4 + k * M_ + m] += pm.x * in[m].x + pm.y * in[m].y
                                     + pm.z * in[m].z + pm.w * in[m].w;
        }
    }

    // 2-stage butterfly (off 32,16): lanes 0..15 hold sums over lane≡l (mod 16).
#pragma unroll
    for (int off = 32; off >= 16; off >>= 1) {
#pragma unroll
        for (int i = 0; i < NV; ++i)
            val[i] += __shfl_down(val[i], off, 64);
    }

    __shared__ float smem[TPB / 64][16][NV + 1];   // +1 pad: conflict-free writes
    const int lane = threadIdx.x & 63;
    const int wave = threadIdx.x >> 6;
    if (lane < 16) {
#pragma unroll
        for (int i = 0; i < NV; ++i) smem[wave][lane][i] = val[i];
    }
    __syncthreads();

    if (threadIdx.x < NV) {
        float s = 0.0f;
#pragma unroll
        for (int w = 0; w < TPB / 64; ++w)
#pragma unroll
            for (int l = 0; l < 16; ++l)
                s += smem[w][l][threadIdx.x];
        ws[(size_t)blockIdx.x * NV + threadIdx.x] = s;   // private slot, no atomic
    }
}

// One block. Phase 1: 256 threads reduce ws[2048][16] over chunks (float4 along
// the 16-value axis). Phase 2: one wave, lane b owns batch b, shuffle-reduce.
__global__ __launch_bounds__(256) void finalize_kernel(
    const float* __restrict__ ws,       // [B*CHUNKS,NV]
    const float* __restrict__ mu_data,  // [K,M]
    float* __restrict__ out)            // [1]
{
    __shared__ float sums[B_][NV];      // 4 KB
    const int t = threadIdx.x;

    // 256 threads == 64 b × 4 float4-groups: thread owns (b, i4)
    {
        const int b  = t >> 2;
        const int i4 = (t & 3) * 4;
        float4 acc = make_float4(0.f, 0.f, 0.f, 0.f);
        for (int c = 0; c < CHUNKS; ++c) {
            const float4 v = *reinterpret_cast<const float4*>(
                ws + ((size_t)(b * CHUNKS + c) * NV + i4));
            acc.x += v.x; acc.y += v.y; acc.z += v.z; acc.w += v.w;
        }
        sums[b][i4 + 0] = acc.x;
        sums[b][i4 + 1] = acc.y;
        sums[b][i4 + 2] = acc.z;
        sums[b][i4 + 3] = acc.w;
    }
    __syncthreads();

    if (t < B_) {                        // one wave: lane b owns batch element b
        const int b = t;
        float r[KM];
#pragma unroll
        for (int k = 0; k < K_; ++k) {
            const float inv = 1.0f / (sums[b][k] + 1e-10f);
#pragma unroll
            for (int m = 0; m < M_; ++m)
                r[k * M_ + m] = sums[b][K_ + k * M_ + m] * inv;
        }
#pragma unroll
        for (int off = 32; off > 0; off >>= 1) {
#pragma unroll
            for (int i = 0; i < KM; ++i)
                r[i] += __shfl_down(r[i], off, 64);
        }
        if (b == 0) {
            float s = 0.0f;
#pragma unroll
            for (int i = 0; i < KM; ++i) {
                const float d = mu_data[i] - r[i] * (1.0f / (float)B_);
                s += d * d;
            }
            out[0] = s;
        }
    }
}

extern "C" void kernel_launch(void* const* d_in, const int* in_sizes, int n_in,
                              void* d_out, int out_size, void* d_ws, size_t ws_size,
                              hipStream_t stream) {
    const float* pred    = (const float*)d_in[0];  // [64,4,256,256] f32
    const float* inp     = (const float*)d_in[1];  // [64,3,256,256] f32
    const int*   heart   = (const int*)d_in[2];    // [64,1,256,256] i32
    const float* mu_data = (const float*)d_in[3];  // [4,3] f32
    float* out = (float*)d_out;

    float* ws = (float*)d_ws;                      // [GRID_][NV] = 128 KB

    partial_kernel<<<GRID_, TPB, 0, stream>>>(pred, inp, heart, ws);
    finalize_kernel<<<1, 256, 0, stream>>>(ws, mu_data, out);
}

// Round 5
// 144.643 us; speedup vs baseline: 1.0110x; 1.0110x over previous
//
#include <hip/hip_runtime.h>

// Problem constants (fixed by reference setup_inputs)
#define B_     64
#define K_     4
#define M_     3
#define NPIX   65536      // X*Y = 256*256
#define CHUNKS 32         // blocks per image -> grid = 2048 = 8 blocks/CU
#define GRID_  (B_ * CHUNKS)
#define TPB    256
#define ITERS  2          // pixels/thread = ITERS*4 = 8
#define NV     16         // 4 den + 12 num partials per thread
#define KM     (K_ * M_)

typedef float f32x4 __attribute__((ext_vector_type(4)));
typedef int   i32x4 __attribute__((ext_vector_type(4)));

// SYSTEM-scope non-temporal load: CPol {sc1,sc0}=11 -> system scope, which
// cannot be served by / installed in the device-level MALL; nt additionally
// marks it non-temporal for L2. Theory (round-4): our input reads allocating
// in the MALL evict ~190 MB/iter of dirty harness poison -> HBM writeback
// that saturates the bus during this kernel. System-scope streaming reads
// should leave the poison dirty-resident (overwritten in place by the next
// fill, never drained). Falsifiable signature: FETCH_SIZE 65.5 -> ~131 MB.
#define STREAM_LOAD(dst, base, voff)                                   \
    asm volatile("global_load_dwordx4 %0, %1, %2 sc0 sc1 nt"           \
                 : "=&v"(dst) : "v"(voff), "s"(base))

__global__ __launch_bounds__(TPB) void partial_kernel(
    const float* __restrict__ pred,    // [B,K,NPIX]
    const float* __restrict__ inp,     // [B,M,NPIX]
    const int*   __restrict__ heart,   // [B,NPIX]
    float* __restrict__ ws)            // [GRID_,NV]
{
    const int b     = blockIdx.x >> 5;           // / CHUNKS
    const int chunk = blockIdx.x & (CHUNKS - 1);
    const int voff  = (int)threadIdx.x * 16;     // byte offset within 1024-px span

    // val[0..3] = den[k]; val[4 + k*3 + m] = num[k][m]
    float val[NV];
#pragma unroll
    for (int i = 0; i < NV; ++i) val[i] = 0.0f;

#pragma unroll
    for (int it = 0; it < ITERS; ++it) {
        const int pixbase = chunk * (NPIX / CHUNKS) + it * (TPB * 4);

        const int*   hb = heart + (size_t)b * NPIX + pixbase;
        const float* ib0 = inp + ((size_t)b * M_ + 0) * NPIX + pixbase;
        const float* ib1 = inp + ((size_t)b * M_ + 1) * NPIX + pixbase;
        const float* ib2 = inp + ((size_t)b * M_ + 2) * NPIX + pixbase;
        const float* pb0 = pred + ((size_t)b * K_ + 0) * NPIX + pixbase;
        const float* pb1 = pred + ((size_t)b * K_ + 1) * NPIX + pixbase;
        const float* pb2 = pred + ((size_t)b * K_ + 2) * NPIX + pixbase;
        const float* pb3 = pred + ((size_t)b * K_ + 3) * NPIX + pixbase;

        i32x4 h;
        f32x4 in0, in1, in2, p0, p1, p2, p3;
        STREAM_LOAD(h,   hb,  voff);
        STREAM_LOAD(in0, ib0, voff);
        STREAM_LOAD(in1, ib1, voff);
        STREAM_LOAD(in2, ib2, voff);
        STREAM_LOAD(p0,  pb0, voff);
        STREAM_LOAD(p1,  pb1, voff);
        STREAM_LOAD(p2,  pb2, voff);
        STREAM_LOAD(p3,  pb3, voff);
        asm volatile("s_waitcnt vmcnt(0)" ::: "memory");
        __builtin_amdgcn_sched_barrier(0);

        const float mx = (h.x == 1) ? 1.0f : 0.0f;
        const float my = (h.y == 1) ? 1.0f : 0.0f;
        const float mz = (h.z == 1) ? 1.0f : 0.0f;
        const float mw = (h.w == 1) ? 1.0f : 0.0f;

        f32x4 in[M_] = {in0, in1, in2};
        f32x4 pr[K_] = {p0, p1, p2, p3};

#pragma unroll
        for (int k = 0; k < K_; ++k) {
            f32x4 pm;
            pm.x = pr[k].x * mx; pm.y = pr[k].y * my;
            pm.z = pr[k].z * mz; pm.w = pr[k].w * mw;
            val[k] += (pm.x + pm.y) + (pm.z + pm.w);
#pragma unroll
            for (int m = 0; m < M_; ++m)
                val[4 + k * M_ + m] += pm.x * in[m].x + pm.y * in[m].y
                                     + pm.z * in[m].z + pm.w * in[m].w;
        }
    }

    // 2-stage butterfly (off 32,16): lanes 0..15 hold sums over lane≡l (mod 16).
#pragma unroll
    for (int off = 32; off >= 16; off >>= 1) {
#pragma unroll
        for (int i = 0; i < NV; ++i)
            val[i] += __shfl_down(val[i], off, 64);
    }

    __shared__ float smem[TPB / 64][16][NV + 1];   // +1 pad: conflict-free writes
    const int lane = threadIdx.x & 63;
    const int wave = threadIdx.x >> 6;
    if (lane < 16) {
#pragma unroll
        for (int i = 0; i < NV; ++i) smem[wave][lane][i] = val[i];
    }
    __syncthreads();

    if (threadIdx.x < NV) {
        float s = 0.0f;
#pragma unroll
        for (int w = 0; w < TPB / 64; ++w)
#pragma unroll
            for (int l = 0; l < 16; ++l)
                s += smem[w][l][threadIdx.x];
        ws[(size_t)blockIdx.x * NV + threadIdx.x] = s;   // private slot, no atomic
    }
}

// One block. Phase 1: 256 threads reduce ws[2048][16] over chunks (float4 along
// the 16-value axis). Phase 2: one wave, lane b owns batch b, shuffle-reduce.
__global__ __launch_bounds__(256) void finalize_kernel(
    const float* __restrict__ ws,       // [B*CHUNKS,NV]
    const float* __restrict__ mu_data,  // [K,M]
    float* __restrict__ out)            // [1]
{
    __shared__ float sums[B_][NV];      // 4 KB
    const int t = threadIdx.x;

    // 256 threads == 64 b × 4 float4-groups: thread owns (b, i4)
    {
        const int b  = t >> 2;
        const int i4 = (t & 3) * 4;
        float4 acc = make_float4(0.f, 0.f, 0.f, 0.f);
        for (int c = 0; c < CHUNKS; ++c) {
            const float4 v = *reinterpret_cast<const float4*>(
                ws + ((size_t)(b * CHUNKS + c) * NV + i4));
            acc.x += v.x; acc.y += v.y; acc.z += v.z; acc.w += v.w;
        }
        sums[b][i4 + 0] = acc.x;
        sums[b][i4 + 1] = acc.y;
        sums[b][i4 + 2] = acc.z;
        sums[b][i4 + 3] = acc.w;
    }
    __syncthreads();

    if (t < B_) {                        // one wave: lane b owns batch element b
        const int b = t;
        float r[KM];
#pragma unroll
        for (int k = 0; k < K_; ++k) {
            const float inv = 1.0f / (sums[b][k] + 1e-10f);
#pragma unroll
            for (int m = 0; m < M_; ++m)
                r[k * M_ + m] = sums[b][K_ + k * M_ + m] * inv;
        }
#pragma unroll
        for (int off = 32; off > 0; off >>= 1) {
#pragma unroll
            for (int i = 0; i < KM; ++i)
                r[i] += __shfl_down(r[i], off, 64);
        }
        if (b == 0) {
            float s = 0.0f;
#pragma unroll
            for (int i = 0; i < KM; ++i) {
                const float d = mu_data[i] - r[i] * (1.0f / (float)B_);
                s += d * d;
            }
            out[0] = s;
        }
    }
}

extern "C" void kernel_launch(void* const* d_in, const int* in_sizes, int n_in,
                              void* d_out, int out_size, void* d_ws, size_t ws_size,
                              hipStream_t stream) {
    const float* pred    = (const float*)d_in[0];  // [64,4,256,256] f32
    const float* inp     = (const float*)d_in[1];  // [64,3,256,256] f32
    const int*   heart   = (const int*)d_in[2];    // [64,1,256,256] i32
    const float* mu_data = (const float*)d_in[3];  // [4,3] f32
    float* out = (float*)d_out;

    float* ws = (float*)d_ws;                      // [GRID_][NV] = 128 KB

    partial_kernel<<<GRID_, TPB, 0, stream>>>(pred, inp, heart, ws);
    finalize_kernel<<<1, 256, 0, stream>>>(ws, mu_data, out);
}